// Round 5
// baseline (909.208 us; speedup 1.0000x reference)
//
#include <hip/hip_runtime.h>

typedef unsigned short u16;
typedef __bf16 v8bf __attribute__((ext_vector_type(8)));
typedef float v4f __attribute__((ext_vector_type(4)));
typedef u16 v8u16 __attribute__((ext_vector_type(8)));

// ---------------- geometry constants ----------------
// X (input): [512][18][18][18*18] fp32, plane (z,w) = 324 contiguous
#define X_B 104976   // 18*18*324
#define X_A 5832     // 18*324
#define X_P 324
// Xb (bf16, padded plane 324->328 for 16B alignment of plane bases)
#define XB_B 106272  // 18*18*328
#define XB_A 5904    // 18*328
#define XB_P 328
#define XB_ELEMS 54411328u   // 512*106272 + 64 tail pad
// GEMM: M=18432 (b,x,y), N=112 (108 used: o*36+zo*6+wo), K'=169*352=59488
#define KP 59488
#define SLAB 352
#define NPAD 112
#define B2_ELEMS 6662656u    // 112*59488
#define C_ELEMS 2064384u     // 18432*112
// old slow-path grid
#define KSPLIT 7
#define NBLK (72 * KSPLIT)
// fast-path grid: 74 m-tiles (7 b = 252 rows each) x 13 kx-splits
#define MT_FAST 74
#define NBLK_FAST (74 * 13)
// ws layout (bytes)
#define WS_C   0
#define WS_B2  8257536ull
#define WS_XB  21582848ull
#define WS_FAST_NEED 130405504ull

__device__ __forceinline__ u16 f2bf(float f) {
    unsigned u = __builtin_bit_cast(unsigned, f);
    u += 0x7fffu + ((u >> 16) & 1u);   // RNE
    return (u16)(u >> 16);
}

#define AS1C(p) (const __attribute__((address_space(1))) void*)(p)
#define AS3(p)  (__attribute__((address_space(3))) void*)(p)
// s_waitcnt imm: vmcnt[3:0], expcnt[6:4]=7 (no wait), lgkmcnt[11:8]=15 (no wait)
#define WAIT_VM3 0x0F73
#define WAIT_VM2 0x0F72
#define WAIT_VM1 0x0F71
#define WAIT_VM0 0x0F70

// ---------------- prep: x fp32 -> padded bf16 (vectorized: v8u16 stores) ----
__global__ void conv_bf16_kernel(const float* __restrict__ X, u16* __restrict__ Xb) {
    const int bx = blockIdx.x;             // 0..9215 = 512*18
    // zero the 64-elem tail pad once (prevents NaN garbage * 0 in MFMA)
    if (bx == 0 && threadIdx.x < 64) Xb[54411264u + threadIdx.x] = 0;
    const long xbbase = (long)bx * XB_A;
    const long xfbase = (long)bx * X_A;
    for (int s = threadIdx.x; s < 738; s += 256) {
        int y = s / 41;                    // 328/8 = 41 slots per plane row
        int pos = (s - y * 41) * 8;        // 0..320, multiple of 8
        const float* src = X + xfbase + y * 324 + pos;
        float4 lo = *(const float4*)src;                       // pos+3 <= 323 always
        float4 hi = (pos + 4 < 324) ? *(const float4*)(src + 4)
                                    : make_float4(0.f, 0.f, 0.f, 0.f);
        v8u16 p;
        p[0] = f2bf(lo.x); p[1] = f2bf(lo.y); p[2] = f2bf(lo.z); p[3] = f2bf(lo.w);
        p[4] = f2bf(hi.x); p[5] = f2bf(hi.y); p[6] = f2bf(hi.z); p[7] = f2bf(hi.w);
        *(v8u16*)(Xb + xbbase + s * 8) = p;
    }
}

// ---------------- prep: Toeplitz weight B2[n][k'] bf16 (v8 stores), + zero C
__global__ void build_b2_kernel(const float* __restrict__ W, u16* __restrict__ B2,
                                float* __restrict__ C) {
    unsigned t = blockIdx.x * 256u + threadIdx.x;
    if (t < 516096u) ((float4*)C)[t] = make_float4(0.f, 0.f, 0.f, 0.f);
    if (t >= 832832u) return;              // B2_ELEMS/8
    unsigned n = t / 7436u;                // KP/8
    unsigned k0 = (t - n * 7436u) * 8u;
    unsigned slab = k0 / 352u;
    unsigned jj0 = k0 - slab * 352u;       // multiple of 8
    v8u16 out = {0, 0, 0, 0, 0, 0, 0, 0};
    if (n < 108u && jj0 < 324u) {
        unsigned kx = slab / 13u, ky = slab - kx * 13u;
        unsigned o = n / 36u, zw = n - o * 36u;
        unsigned zo = zw / 6u, wo = zw - zo * 6u;
        const float* wb = W + o * 28561u + kx * 2197u + ky * 169u;
#pragma unroll
        for (int e = 0; e < 8; ++e) {
            unsigned jj = jj0 + e;
            if (jj < 324u) {
                unsigned jz = jj / 18u, jw = jj - jz * 18u;
                int dz = (int)jz - (int)zo, dw = (int)jw - (int)wo;
                if (dz >= 0 && dz < 13 && dw >= 0 && dw < 13)
                    out[e] = f2bf(wb[dz * 13 + dw]);
            }
        }
    }
    ((v8u16*)B2)[t] = out;
}

// ---------------- fast GEMM: kx-major K-grouping with si-sliced A reuse ----
// Block = (mt, kx): 7 consecutive b (252 rows, padded to 256 for MFMA grid),
// K-range = slabs (kx, ky=0..12). K order: si-major, ky-minor.
// For fixed (kx, si), the A-data for ALL 13 ky steps is the chunk-si slice of
// plane rows [kx,kx+6) x cols [0,18): 7b*108 planes * 64B = 48.4 KB.
// Staged ONCE per si (spread over ky steps 0..5, double buffered) -> A global
// traffic drops 4.3x vs per-slab im2col staging (0.51 GB vs 2.14 GB).
// B tile (112x32, 7 KB) staged per step, triple-buffered, depth-2 pipeline.
// Counted vmcnt: N = #loads issued after B[g]; N=0 at the final step (g=142)
// because B[143] is never issued (drain fully - race otherwise).
__global__ __launch_bounds__(512, 2) void gemm_conv_fast(
    const u16* __restrict__ Xb, const u16* __restrict__ B2, float* __restrict__ C)
{
    // A slice buffers: slot = bl*432 + p*4 + pos (p = prow*18+pcol, pos = chunk
    // position after XOR swizzle), 8 bf16 per slot. 3072 slots incl. 48 pad
    // slots (staging step ky=5 writes 512 slots but only 464 are real; pad
    // slots get cloned data so per-wave vmcnt counts stay uniform, no branch).
    __shared__ u16 Alds[2][3072 * 8];      // 2 x 49152 B
    __shared__ u16 Blds[3][112 * 32];      // 3 x 7168 B   -> total 119.8 KB

    const int tid = threadIdx.x;
    const int lane = tid & 63;
    const int wv = tid >> 6;               // 0..7
    const int bwv = (wv < 7) ? wv : 6;     // wave 7 duplicates wave 6's B load
    const int mt = blockIdx.x % MT_FAST;
    const int kx = blockIdx.x / MT_FAST;   // 0..12
    const int b0 = mt * 7;

    // ---- B staging lane (identical swizzle to verified kernel) ----
    const int bslot = bwv * 64 + lane;
    const int chunkB = (bslot & 3) ^ ((bslot >> 3) & 3);
    const u16* laneBp = B2 + ((bslot >> 2) * KP + chunkB * 8 + kx * 13 * SLAB);

    // ---- MFMA A-fragment bases ----
    // lane holds A[row][si*32 + (lane>>4)*8 .. +7]; row -> (bl, x, y);
    // plane index p = x*18 + (y+ky); LDS chunk position = fc ^ ((p>>1)&3).
    // Window = 4*(p&1) | pos: the 4 fc-groups share the same 16 p-values and
    // the XOR rotates them across all 4 windows per parity -> 8 word-accesses
    // per bank per instr, i.e. zero excess conflicts.
    int fr_base[2], fr_p0[2];
#pragma unroll
    for (int i = 0; i < 2; ++i) {
        int row = wv * 32 + i * 16 + (lane & 15);
        if (row > 251) row = 251;          // pad rows duplicate row 251 (masked at C-write)
        int bl = row / 36, xy = row - bl * 36;
        int x = xy / 6, y = xy - x * 6;
        fr_p0[i] = x * 18 + y;
        fr_base[i] = bl * 432;
    }
    const int fc = lane >> 4;

    // ---- A slice staging: step j in [0,6), slot q = j*512 + tid ----
    auto stageA = [&](int snext, int j, int nb) {
        int q = j * 512 + tid;
        int qe = (q >= 3024) ? q - 3024 : q;    // pad slots clone slot 0..47
        int bl = qe / 432;                      // 0..6
        int rem = qe - bl * 432;
        int p = rem >> 2;                       // 0..107
        int pos = rem & 3;
        int c = pos ^ ((p >> 1) & 3);           // global chunk held at this pos
        int b = b0 + bl; if (b > 511) b = 511;  // tile 73 clamp
        int prow = p / 18;
        int pcol = p - prow * 18;
        const u16* gp = Xb + (b * XB_B + (kx + prow) * XB_A + pcol * XB_P
                              + snext * 32 + c * 8);
        __builtin_amdgcn_global_load_lds(AS1C(gp),
            AS3(&Alds[nb][(j * 512 + wv * 64) * 8]), 16, 0, 0);
    };
    auto stageB = [&](int si_, int ky_, int pb_) {
        const u16* gp = laneBp + (ky_ * SLAB + si_ * 32);
        __builtin_amdgcn_global_load_lds(AS1C(gp),
            AS3(&Blds[pb_][(bwv * 64) * 8]), 16, 0, 0);
    };

    v4f acc[2][7];
#pragma unroll
    for (int i = 0; i < 2; ++i)
#pragma unroll
        for (int t = 0; t < 7; ++t) acc[i][t] = (v4f){0.f, 0.f, 0.f, 0.f};

    // ---- prologue: full slice si=0 (6 issues/thread), then B[0], B[1] ----
#pragma unroll
    for (int j = 0; j < 6; ++j) stageA(0, j, 0);
    stageB(0, 0, 0);
    stageB(0, 1, 1);

    int si = 0, ky = 0;        // current step g = si*13 + ky
    int si2 = 0, ky2 = 2;      // step g+2 (B prefetch target)
    int pb = 0, pb2 = 2;       // Blds buffer for g and g+2

    for (int g = 0; g < 143; ++g) {
        // Allowed outstanding = loads issued after B[g] (issued at step g-2):
        // B[g+1] at g-1 (absent for g=142!), A-chunk at g-1 (ky in [1,6]),
        // A-chunk at g-2 (ky in [2,7]); A only while si<10.
        int N;
        if (g >= 142) {
            N = 0;                           // final step: B[143] never issued
        } else {
            N = 1;
            if (si < 10) {
                if (ky >= 1 && ky <= 6) ++N; // A-chunk issued at g-1
                if (ky >= 2 && ky <= 7) ++N; // A-chunk issued at g-2
            }
        }
        if (N == 0)      __builtin_amdgcn_s_waitcnt(WAIT_VM0);
        else if (N == 1) __builtin_amdgcn_s_waitcnt(WAIT_VM1);
        else if (N == 2) __builtin_amdgcn_s_waitcnt(WAIT_VM2);
        else             __builtin_amdgcn_s_waitcnt(WAIT_VM3);
        __builtin_amdgcn_s_barrier();

        if (g + 2 < 143) stageB(si2, ky2, pb2);
        if (ky < 6 && si < 10) stageA(si + 1, ky, (si + 1) & 1);

        const int ab = si & 1;
        v8bf a[2];
#pragma unroll
        for (int i = 0; i < 2; ++i) {
            int p = fr_p0[i] + ky;                               // 0..107
            int slot = fr_base[i] + p * 4 + (fc ^ ((p >> 1) & 3));
            a[i] = *(const v8bf*)(&Alds[ab][slot * 8]);
        }
#pragma unroll
        for (int t = 0; t < 7; ++t) {
            int row = t * 16 + (lane & 15);
            int slot = row * 4 + ((lane >> 4) ^ ((row >> 1) & 3));
            v8bf bb = *(const v8bf*)(&Blds[pb][slot * 8]);
#pragma unroll
            for (int i = 0; i < 2; ++i)
                acc[i][t] = __builtin_amdgcn_mfma_f32_16x16x32_bf16(a[i], bb, acc[i][t], 0, 0, 0);
        }

        if (++ky == 13) { ky = 0; ++si; }
        if (++ky2 == 13) { ky2 = 0; ++si2; }
        if (++pb == 3) pb = 0;
        if (++pb2 == 3) pb2 = 0;
    }

    // ---- split-K accumulate into C (mask pad rows 252..255 and tile-73 tail)
    const int colb = lane & 15;
    const int rq = (lane >> 4) * 4;
#pragma unroll
    for (int i = 0; i < 2; ++i) {
        int rl0 = wv * 32 + i * 16 + rq;
#pragma unroll
        for (int t = 0; t < 7; ++t) {
            int col = t * 16 + colb;
#pragma unroll
            for (int gq = 0; gq < 4; ++gq) {
                int lr = rl0 + gq;
                int grow = mt * 252 + lr;
                if (lr < 252 && grow < 18432)
                    atomicAdd(&C[grow * NPAD + col], acc[i][t][gq]);
            }
        }
    }
}

// ---------------- slow-path GEMM (small-ws fallback, fp32 reg-staging) ----
template<bool USE_XB>
__global__ __launch_bounds__(512, 4) void gemm_conv(
    const u16* __restrict__ Xb, const float* __restrict__ Xf,
    const u16* __restrict__ B2, float* __restrict__ C)
{
    __shared__ u16 Alds[3][256 * 32];
    __shared__ u16 Blds[3][112 * 32];

    const int tid = threadIdx.x;
    const int lane = tid & 63;
    const int wv = tid >> 6;
    const int bwv = (wv < 7) ? wv : 6;
    const int mt = blockIdx.x % 72;
    const int ks = blockIdx.x / 72;

    const int sbeg = (ks * 169) / KSPLIT;
    const int send = ((ks + 1) * 169) / KSPLIT;
    const int nsteps = (send - sbeg) * 11;

    int laneA[2], chunkA[2];
#pragma unroll
    for (int jr = 0; jr < 2; ++jr) {
        int slot = jr * 512 + tid;
        int row = slot >> 2;
        int chunk = (slot & 3) ^ ((slot >> 3) & 3);
        int r = mt * 256 + row;
        int b = r / 36;
        int xy = r - b * 36;
        int x = xy / 6;
        int y = xy - x * 6;
        if (USE_XB) laneA[jr] = b * XB_B + x * XB_A + y * XB_P + chunk * 8;
        else        laneA[jr] = b * X_B + x * X_A + y * X_P;
        chunkA[jr] = chunk;
    }
    const int bslot = bwv * 64 + lane;
    const int chunkB = (bslot & 3) ^ ((bslot >> 3) & 3);
    const int laneB = (bslot >> 2) * KP + chunkB * 8;

    v4f acc[2][7];
#pragma unroll
    for (int i = 0; i < 2; ++i)
#pragma unroll
        for (int t = 0; t < 7; ++t) acc[i][t] = (v4f){0.f, 0.f, 0.f, 0.f};

    auto stage = [&](int step, int p) {
        int q = step / 11;
        int si = step - q * 11;
        int slab = sbeg + q;
        int kx = slab / 13;
        int ky = slab - kx * 13;
        if (USE_XB) {
            int aofs = kx * XB_A + ky * XB_P + si * 32;
#pragma unroll
            for (int jr = 0; jr < 2; ++jr) {
                const u16* gp = Xb + (laneA[jr] + aofs);
                __builtin_amdgcn_global_load_lds(AS1C(gp), AS3(&Alds[p][(jr * 512 + wv * 64) * 8]), 16, 0, 0);
            }
        } else {
            int aofs = kx * X_A + ky * X_P;
#pragma unroll
            for (int jr = 0; jr < 2; ++jr) {
                int jj0 = si * 32 + chunkA[jr] * 8;
                const float* gp = Xf + (laneA[jr] + aofs);
                float4 lo = make_float4(0.f, 0.f, 0.f, 0.f);
                float4 hi = make_float4(0.f, 0.f, 0.f, 0.f);
                if (jj0 < 324)     lo = *(const float4*)(gp + jj0);
                if (jj0 + 4 < 324) hi = *(const float4*)(gp + jj0 + 4);
                v8u16 pk;
                pk[0] = f2bf(lo.x); pk[1] = f2bf(lo.y); pk[2] = f2bf(lo.z); pk[3] = f2bf(lo.w);
                pk[4] = f2bf(hi.x); pk[5] = f2bf(hi.y); pk[6] = f2bf(hi.z); pk[7] = f2bf(hi.w);
                int slot = jr * 512 + tid;
                *(v8u16*)(&Alds[p][slot * 8]) = pk;
            }
        }
        int bofs = slab * SLAB + si * 32;
        const u16* gp0 = B2 + (laneB + bofs);
        __builtin_amdgcn_global_load_lds(AS1C(gp0), AS3(&Blds[p][(bwv * 64) * 8]), 16, 0, 0);
    };

    stage(0, 0);
    stage(1, 1);

    for (int step = 0; step < nsteps; ++step) {
        const int p = step % 3;
        if (USE_XB) {
            if (step + 1 < nsteps) __builtin_amdgcn_s_waitcnt(WAIT_VM3);
            else                   __builtin_amdgcn_s_waitcnt(WAIT_VM0);
        } else {
            __builtin_amdgcn_s_waitcnt(0);
        }
        __builtin_amdgcn_s_barrier();
        if (step + 2 < nsteps) stage(step + 2, (step + 2) % 3);

        v8bf a[2];
#pragma unroll
        for (int i = 0; i < 2; ++i) {
            int row = wv * 32 + i * 16 + (lane & 15);
            int slot = row * 4 + ((lane >> 4) ^ ((row >> 1) & 3));
            a[i] = *(const v8bf*)(&Alds[p][slot * 8]);
        }
#pragma unroll
        for (int t = 0; t < 7; ++t) {
            int row = t * 16 + (lane & 15);
            int slot = row * 4 + ((lane >> 4) ^ ((row >> 1) & 3));
            v8bf bb = *(const v8bf*)(&Blds[p][slot * 8]);
#pragma unroll
            for (int i = 0; i < 2; ++i)
                acc[i][t] = __builtin_amdgcn_mfma_f32_16x16x32_bf16(a[i], bb, acc[i][t], 0, 0, 0);
        }
    }

    const int colb = lane & 15;
    const int rq = (lane >> 4) * 4;
#pragma unroll
    for (int i = 0; i < 2; ++i) {
        int rowb = mt * 256 + wv * 32 + i * 16 + rq;
#pragma unroll
        for (int t = 0; t < 7; ++t) {
            int col = t * 16 + colb;
#pragma unroll
            for (int g = 0; g < 4; ++g)
                atomicAdd(&C[(rowb + g) * NPAD + col], acc[i][t][g]);
        }
    }
}

// ---------------- fused bias+ReLU+linear+sigmoid ----------------
__global__ void epilogue_kernel(const float* __restrict__ C, const float* __restrict__ cb,
                                const float* __restrict__ lw, const float* __restrict__ lb,
                                float* __restrict__ out) {
    const int b = blockIdx.x;
    const int tid = threadIdx.x;
    float s = 0.f;
    for (int t = tid; t < 3888; t += 256) {
        int xy = t / 108, n = t - xy * 108;
        int o = n / 36, zw = n - o * 36;
        int x = xy / 6, y = xy - x * 6;
        float c = C[(b * 36 + xy) * NPAD + n] + cb[o];
        s += fmaxf(c, 0.f) * lw[o * 1296 + x * 216 + y * 36 + zw];
    }
#pragma unroll
    for (int off = 32; off > 0; off >>= 1) s += __shfl_down(s, off, 64);
    __shared__ float red[4];
    if ((tid & 63) == 0) red[tid >> 6] = s;
    __syncthreads();
    if (tid == 0)
        out[b] = 1.f / (1.f + expf(-(red[0] + red[1] + red[2] + red[3] + lb[0])));
}

extern "C" void kernel_launch(void* const* d_in, const int* in_sizes, int n_in,
                              void* d_out, int out_size, void* d_ws, size_t ws_size,
                              hipStream_t stream) {
    const float* X  = (const float*)d_in[0];
    const float* W  = (const float*)d_in[1];
    const float* cb = (const float*)d_in[2];
    const float* lw = (const float*)d_in[3];
    const float* lb = (const float*)d_in[4];
    float* out = (float*)d_out;
    char* ws = (char*)d_ws;
    float* C  = (float*)(ws + WS_C);
    u16* B2   = (u16*)(ws + WS_B2);
    u16* Xb   = (u16*)(ws + WS_XB);
    const bool fast = ws_size >= WS_FAST_NEED;

    build_b2_kernel<<<3254, 256, 0, stream>>>(W, B2, C);
    if (fast) {
        conv_bf16_kernel<<<9216, 256, 0, stream>>>(X, Xb);
        gemm_conv_fast<<<NBLK_FAST, 512, 0, stream>>>(Xb, B2, C);
    } else {
        gemm_conv<false><<<NBLK, 512, 0, stream>>>(nullptr, X, B2, C);
    }
    epilogue_kernel<<<512, 256, 0, stream>>>(C, cb, lw, lb, out);
}

// Round 6
// 688.638 us; speedup vs baseline: 1.3203x; 1.3203x over previous
//
#include <hip/hip_runtime.h>

typedef unsigned short u16;
typedef __bf16 v8bf __attribute__((ext_vector_type(8)));
typedef float v4f __attribute__((ext_vector_type(4)));
typedef u16 v8u16 __attribute__((ext_vector_type(8)));

// ---------------- geometry constants ----------------
// X (input): [512][18][18][18*18] fp32, plane (z,w) = 324 contiguous
#define X_B 104976   // 18*18*324
#define X_A 5832     // 18*324
#define X_P 324
// Xb (bf16, padded plane 324->328 for 16B alignment of plane bases)
#define XB_B 106272  // 18*18*328
#define XB_A 5904    // 18*328
#define XB_P 328
#define XB_ELEMS 54411328u   // 512*106272 + 64 tail pad
// GEMM: M=18432 (b,x,y), N=112 (108 used: o*36+zo*6+wo), K'=169*352=59488
#define KP 59488
#define SLAB 352
#define NPAD 112
#define B2_ELEMS 6662656u    // 112*59488 == 13*143*3584 (B3 layout, same size)
#define C_ELEMS 2064384u     // 18432*112
// old slow-path grid
#define KSPLIT 7
#define NBLK (72 * KSPLIT)
// fast-path grid: 74 m-tiles (7 b = 252 rows each) x 13 kx-splits
#define MT_FAST 74
#define NBLK_FAST (74 * 13)
// ws layout (bytes)
#define WS_C   0
#define WS_B2  8257536ull
#define WS_XB  21582848ull
#define WS_FAST_NEED 130405504ull

__device__ __forceinline__ u16 f2bf(float f) {
    unsigned u = __builtin_bit_cast(unsigned, f);
    u += 0x7fffu + ((u >> 16) & 1u);   // RNE
    return (u16)(u >> 16);
}

#define AS1C(p) (const __attribute__((address_space(1))) void*)(p)
#define AS3(p)  (__attribute__((address_space(3))) void*)(p)
// s_waitcnt imm: vmcnt[3:0], expcnt[6:4]=7 (no wait), lgkmcnt[11:8]=15 (no wait)
#define WAIT_VM3 0x0F73
#define WAIT_VM2 0x0F72
#define WAIT_VM1 0x0F71
#define WAIT_VM0 0x0F70

// ---------------- prep: x fp32 -> padded bf16 (vectorized: v8u16 stores) ----
__global__ void conv_bf16_kernel(const float* __restrict__ X, u16* __restrict__ Xb) {
    const int bx = blockIdx.x;             // 0..9215 = 512*18
    // zero the 64-elem tail pad once (prevents NaN garbage * 0 in MFMA)
    if (bx == 0 && threadIdx.x < 64) Xb[54411264u + threadIdx.x] = 0;
    const long xbbase = (long)bx * XB_A;
    const long xfbase = (long)bx * X_A;
    for (int s = threadIdx.x; s < 738; s += 256) {
        int y = s / 41;                    // 328/8 = 41 slots per plane row
        int pos = (s - y * 41) * 8;        // 0..320, multiple of 8
        const float* src = X + xfbase + y * 324 + pos;
        float4 lo = *(const float4*)src;                       // pos+3 <= 323 always
        float4 hi = (pos + 4 < 324) ? *(const float4*)(src + 4)
                                    : make_float4(0.f, 0.f, 0.f, 0.f);
        v8u16 p;
        p[0] = f2bf(lo.x); p[1] = f2bf(lo.y); p[2] = f2bf(lo.z); p[3] = f2bf(lo.w);
        p[4] = f2bf(hi.x); p[5] = f2bf(hi.y); p[6] = f2bf(hi.z); p[7] = f2bf(hi.w);
        *(v8u16*)(Xb + xbbase + s * 8) = p;
    }
}

// ---------------- prep: Toeplitz weight bf16 + zero C ----------------
// B3MODE=true: emit tile-contiguous pre-swizzled layout B3[kx][g][bslot*8+e]
//   = exact 7168B LDS image per (kx, g=si*13+ky) step tile -> GEMM stageB is a
//   pure linear streaming copy (no scatter, no over-fetch, no address math).
// B3MODE=false: legacy row-major B2[n][k'] for the slow fallback path.
template<bool B3MODE>
__global__ void build_b2_kernel(const float* __restrict__ W, u16* __restrict__ B2,
                                float* __restrict__ C) {
    unsigned t = blockIdx.x * 256u + threadIdx.x;
    if (t < 516096u) ((float4*)C)[t] = make_float4(0.f, 0.f, 0.f, 0.f);
    if (t >= 832832u) return;              // B2_ELEMS/8 == 13*143*448
    unsigned n, slab, jj0;
    if (B3MODE) {
        unsigned kx = t / 64064u;          // 143*448
        unsigned r = t - kx * 64064u;
        unsigned g = r / 448u;
        unsigned bslot = r - g * 448u;
        n = bslot >> 2;
        unsigned chunk = (bslot & 3u) ^ ((bslot >> 3) & 3u);
        unsigned si = g / 13u, kyq = g - si * 13u;
        slab = kx * 13u + kyq;
        jj0 = si * 32u + chunk * 8u;       // <= 344; per-elem guard below
    } else {
        n = t / 7436u;                     // KP/8
        unsigned k0 = (t - n * 7436u) * 8u;
        slab = k0 / 352u;
        jj0 = k0 - slab * 352u;
    }
    v8u16 out = {0, 0, 0, 0, 0, 0, 0, 0};
    if (n < 108u && jj0 < 324u) {
        unsigned kx = slab / 13u, ky = slab - kx * 13u;
        unsigned o = n / 36u, zw = n - o * 36u;
        unsigned zo = zw / 6u, wo = zw - zo * 6u;
        const float* wb = W + o * 28561u + kx * 2197u + ky * 169u;
#pragma unroll
        for (int e = 0; e < 8; ++e) {
            unsigned jj = jj0 + e;
            if (jj < 324u) {
                unsigned jz = jj / 18u, jw = jj - jz * 18u;
                int dz = (int)jz - (int)zo, dw = (int)jw - (int)wo;
                if (dz >= 0 && dz < 13 && dw >= 0 && dw < 13)
                    out[e] = f2bf(wb[dz * 13 + dw]);
            }
        }
    }
    ((v8u16*)B2)[t] = out;
}

// ---------------- fast GEMM: kx-major, si-sliced A reuse, 2 blocks/CU ------
// R5 counters: 599.8us, Occupancy 21.6% (8 waves/CU, LDS-capped), MfmaUtil 17%,
// VALUBusy 13%, HBM 16% -> latency/occupancy-bound (~2680 cyc/step vs ~900 work).
// Fix: (1) B3 tile-contiguous layout (stageB = linear stream; was 16-way
// 119KB-strided scatter w/ 2x over-fetch); (2) SINGLE-buffered A slice +
// depth-4 B ring -> LDS 76KB -> 2 blocks/CU (16 waves). A slice (48.4KB,
// chunk si of 7b x 108 planes) burst-loaded at each si boundary (10x/block),
// exposed latency covered by the co-resident block.
// vmcnt schedule (audited): steady vmcnt(2) (outstanding B[g..g+2], need B[g],
// issued 3 steps prior; in-order retirement covers all earlier A loads);
// boundary: barrier; burst(6)+stageB(g+3); vmcnt(1); barrier. Tail min(2,142-g).
__global__ __launch_bounds__(512, 4) void gemm_conv_fast(
    const u16* __restrict__ Xb, const u16* __restrict__ B3, float* __restrict__ C)
{
    // A slice: slot = bl*432 + p*4 + pos (p = prow*18+pcol; pos = chunk position
    // after XOR swizzle). 3072 slots incl. 48 pad clones (uniform vmcnt counts).
    __shared__ u16 Alds[3072 * 8];         // 49152 B (single buffer)
    __shared__ u16 Blds[4][112 * 32];      // 4 x 7168 B -> total 76 KB, 2 blk/CU

    const int tid = threadIdx.x;
    const int lane = tid & 63;
    const int wv = tid >> 6;               // 0..7
    const int bwv = (wv < 7) ? wv : 6;     // wave 7 duplicates wave 6's B load
    const int mt = blockIdx.x % MT_FAST;
    const int kx = blockIdx.x / MT_FAST;   // 0..12
    const int b0 = mt * 7;

    // ---- B staging: linear copy of the pre-swizzled 7168B tile ----
    const int bslot = bwv * 64 + lane;
    const u16* laneBp = B3 + ((kx * 143) * 448 + bslot) * 8;

    // ---- MFMA A-fragment bases ----
    // lane holds A[row][si*32 + (lane>>4)*8 .. +7]; row -> (bl, x, y);
    // plane p = x*18 + (y+ky); LDS chunk position = fc ^ ((p>>1)&3).
    int fr_base[2], fr_p0[2];
#pragma unroll
    for (int i = 0; i < 2; ++i) {
        int row = wv * 32 + i * 16 + (lane & 15);
        if (row > 251) row = 251;          // pad rows duplicate row 251 (masked at C-write)
        int bl = row / 36, xy = row - bl * 36;
        int x = xy / 6, y = xy - x * 6;
        fr_p0[i] = x * 18 + y;
        fr_base[i] = bl * 432;
    }
    const int fc = lane >> 4;

    // ---- A slice burst: j in [0,6), slot q = j*512 + tid ----
    auto stageA = [&](int si_, int j) {
        int q = j * 512 + tid;
        int qe = (q >= 3024) ? q - 3024 : q;    // pad slots clone slot 0..47
        int bl = qe / 432;                      // 0..6
        int rem = qe - bl * 432;
        int p = rem >> 2;                       // 0..107
        int pos = rem & 3;
        int c = pos ^ ((p >> 1) & 3);           // global chunk held at this pos
        int b = b0 + bl; if (b > 511) b = 511;  // tile 73 clamp
        int prow = p / 18;
        int pcol = p - prow * 18;
        const u16* gp = Xb + (b * XB_B + (kx + prow) * XB_A + pcol * XB_P
                              + si_ * 32 + c * 8);
        __builtin_amdgcn_global_load_lds(AS1C(gp),
            AS3(&Alds[(j * 512 + wv * 64) * 8]), 16, 0, 0);
    };
    auto stageB = [&](int g_, int pb_) {
        const u16* gp = laneBp + g_ * 3584;     // 448*8 elems per tile
        __builtin_amdgcn_global_load_lds(AS1C(gp),
            AS3(&Blds[pb_][(bwv * 64) * 8]), 16, 0, 0);
    };

    v4f acc[2][7];
#pragma unroll
    for (int i = 0; i < 2; ++i)
#pragma unroll
        for (int t = 0; t < 7; ++t) acc[i][t] = (v4f){0.f, 0.f, 0.f, 0.f};

    // ---- prologue: slice 0 burst, then B[0..2] ----
#pragma unroll
    for (int j = 0; j < 6; ++j) stageA(0, j);
    stageB(0, 0);
    stageB(1, 1);
    stageB(2, 2);

    int si = 0, ky = 0;                    // step g = si*13 + ky

    for (int g = 0; g < 143; ++g) {
        if (ky == 0 && si > 0) {
            // si boundary: all waves done reading slice si-1 after this barrier
            __builtin_amdgcn_s_barrier();
#pragma unroll
            for (int j = 0; j < 6; ++j) stageA(si, j);   // burst slice si
            stageB(g + 3, (g + 3) & 3);                  // g+3 <= 133 here
            __builtin_amdgcn_s_waitcnt(WAIT_VM1);        // drain burst (+B<=g+2)
            __builtin_amdgcn_s_barrier();                // publish slice si
        } else {
            int rem = 142 - g;
            if (rem >= 2)      __builtin_amdgcn_s_waitcnt(WAIT_VM2);
            else if (rem == 1) __builtin_amdgcn_s_waitcnt(WAIT_VM1);
            else               __builtin_amdgcn_s_waitcnt(WAIT_VM0);
            __builtin_amdgcn_s_barrier();
            if (g + 3 < 143) stageB(g + 3, (g + 3) & 3);
        }

        v8bf a[2];
#pragma unroll
        for (int i = 0; i < 2; ++i) {
            int p = fr_p0[i] + ky;                               // 0..107
            int slot = fr_base[i] + p * 4 + (fc ^ ((p >> 1) & 3));
            a[i] = *(const v8bf*)(&Alds[slot * 8]);
        }
        const int pb = g & 3;
#pragma unroll
        for (int t = 0; t < 7; ++t) {
            int row = t * 16 + (lane & 15);
            int slot = row * 4 + ((lane >> 4) ^ ((row >> 1) & 3));
            v8bf bb = *(const v8bf*)(&Blds[pb][slot * 8]);
#pragma unroll
            for (int i = 0; i < 2; ++i)
                acc[i][t] = __builtin_amdgcn_mfma_f32_16x16x32_bf16(a[i], bb, acc[i][t], 0, 0, 0);
        }

        if (++ky == 13) { ky = 0; ++si; }
    }

    // ---- split-K accumulate into C (mask pad rows 252..255 and tile-73 tail)
    const int colb = lane & 15;
    const int rq = (lane >> 4) * 4;
#pragma unroll
    for (int i = 0; i < 2; ++i) {
        int rl0 = wv * 32 + i * 16 + rq;
#pragma unroll
        for (int t = 0; t < 7; ++t) {
            int col = t * 16 + colb;
#pragma unroll
            for (int gq = 0; gq < 4; ++gq) {
                int lr = rl0 + gq;
                int grow = mt * 252 + lr;
                if (lr < 252 && grow < 18432)
                    atomicAdd(&C[grow * NPAD + col], acc[i][t][gq]);
            }
        }
    }
}

// ---------------- slow-path GEMM (small-ws fallback, fp32 reg-staging) ----
template<bool USE_XB>
__global__ __launch_bounds__(512, 4) void gemm_conv(
    const u16* __restrict__ Xb, const float* __restrict__ Xf,
    const u16* __restrict__ B2, float* __restrict__ C)
{
    __shared__ u16 Alds[3][256 * 32];
    __shared__ u16 Blds[3][112 * 32];

    const int tid = threadIdx.x;
    const int lane = tid & 63;
    const int wv = tid >> 6;
    const int bwv = (wv < 7) ? wv : 6;
    const int mt = blockIdx.x % 72;
    const int ks = blockIdx.x / 72;

    const int sbeg = (ks * 169) / KSPLIT;
    const int send = ((ks + 1) * 169) / KSPLIT;
    const int nsteps = (send - sbeg) * 11;

    int laneA[2], chunkA[2];
#pragma unroll
    for (int jr = 0; jr < 2; ++jr) {
        int slot = jr * 512 + tid;
        int row = slot >> 2;
        int chunk = (slot & 3) ^ ((slot >> 3) & 3);
        int r = mt * 256 + row;
        int b = r / 36;
        int xy = r - b * 36;
        int x = xy / 6;
        int y = xy - x * 6;
        if (USE_XB) laneA[jr] = b * XB_B + x * XB_A + y * XB_P + chunk * 8;
        else        laneA[jr] = b * X_B + x * X_A + y * X_P;
        chunkA[jr] = chunk;
    }
    const int bslot = bwv * 64 + lane;
    const int chunkB = (bslot & 3) ^ ((bslot >> 3) & 3);
    const int laneB = (bslot >> 2) * KP + chunkB * 8;

    v4f acc[2][7];
#pragma unroll
    for (int i = 0; i < 2; ++i)
#pragma unroll
        for (int t = 0; t < 7; ++t) acc[i][t] = (v4f){0.f, 0.f, 0.f, 0.f};

    auto stage = [&](int step, int p) {
        int q = step / 11;
        int si = step - q * 11;
        int slab = sbeg + q;
        int kx = slab / 13;
        int ky = slab - kx * 13;
        if (USE_XB) {
            int aofs = kx * XB_A + ky * XB_P + si * 32;
#pragma unroll
            for (int jr = 0; jr < 2; ++jr) {
                const u16* gp = Xb + (laneA[jr] + aofs);
                __builtin_amdgcn_global_load_lds(AS1C(gp), AS3(&Alds[p][(jr * 512 + wv * 64) * 8]), 16, 0, 0);
            }
        } else {
            int aofs = kx * X_A + ky * X_P;
#pragma unroll
            for (int jr = 0; jr < 2; ++jr) {
                int jj0 = si * 32 + chunkA[jr] * 8;
                const float* gp = Xf + (laneA[jr] + aofs);
                float4 lo = make_float4(0.f, 0.f, 0.f, 0.f);
                float4 hi = make_float4(0.f, 0.f, 0.f, 0.f);
                if (jj0 < 324)     lo = *(const float4*)(gp + jj0);
                if (jj0 + 4 < 324) hi = *(const float4*)(gp + jj0 + 4);
                v8u16 pk;
                pk[0] = f2bf(lo.x); pk[1] = f2bf(lo.y); pk[2] = f2bf(lo.z); pk[3] = f2bf(lo.w);
                pk[4] = f2bf(hi.x); pk[5] = f2bf(hi.y); pk[6] = f2bf(hi.z); pk[7] = f2bf(hi.w);
                int slot = jr * 512 + tid;
                *(v8u16*)(&Alds[p][slot * 8]) = pk;
            }
        }
        int bofs = slab * SLAB + si * 32;
        const u16* gp0 = B2 + (laneB + bofs);
        __builtin_amdgcn_global_load_lds(AS1C(gp0), AS3(&Blds[p][(bwv * 64) * 8]), 16, 0, 0);
    };

    stage(0, 0);
    stage(1, 1);

    for (int step = 0; step < nsteps; ++step) {
        const int p = step % 3;
        if (USE_XB) {
            if (step + 1 < nsteps) __builtin_amdgcn_s_waitcnt(WAIT_VM3);
            else                   __builtin_amdgcn_s_waitcnt(WAIT_VM0);
        } else {
            __builtin_amdgcn_s_waitcnt(0);
        }
        __builtin_amdgcn_s_barrier();
        if (step + 2 < nsteps) stage(step + 2, (step + 2) % 3);

        v8bf a[2];
#pragma unroll
        for (int i = 0; i < 2; ++i) {
            int row = wv * 32 + i * 16 + (lane & 15);
            int slot = row * 4 + ((lane >> 4) ^ ((row >> 1) & 3));
            a[i] = *(const v8bf*)(&Alds[p][slot * 8]);
        }
#pragma unroll
        for (int t = 0; t < 7; ++t) {
            int row = t * 16 + (lane & 15);
            int slot = row * 4 + ((lane >> 4) ^ ((row >> 1) & 3));
            v8bf bb = *(const v8bf*)(&Blds[p][slot * 8]);
#pragma unroll
            for (int i = 0; i < 2; ++i)
                acc[i][t] = __builtin_amdgcn_mfma_f32_16x16x32_bf16(a[i], bb, acc[i][t], 0, 0, 0);
        }
    }

    const int colb = lane & 15;
    const int rq = (lane >> 4) * 4;
#pragma unroll
    for (int i = 0; i < 2; ++i) {
        int rowb = mt * 256 + wv * 32 + i * 16 + rq;
#pragma unroll
        for (int t = 0; t < 7; ++t) {
            int col = t * 16 + colb;
#pragma unroll
            for (int g = 0; g < 4; ++g)
                atomicAdd(&C[(rowb + g) * NPAD + col], acc[i][t][g]);
        }
    }
}

// ---------------- fused bias+ReLU+linear+sigmoid ----------------
__global__ void epilogue_kernel(const float* __restrict__ C, const float* __restrict__ cb,
                                const float* __restrict__ lw, const float* __restrict__ lb,
                                float* __restrict__ out) {
    const int b = blockIdx.x;
    const int tid = threadIdx.x;
    float s = 0.f;
    for (int t = tid; t < 3888; t += 256) {
        int xy = t / 108, n = t - xy * 108;
        int o = n / 36, zw = n - o * 36;
        int x = xy / 6, y = xy - x * 6;
        float c = C[(b * 36 + xy) * NPAD + n] + cb[o];
        s += fmaxf(c, 0.f) * lw[o * 1296 + x * 216 + y * 36 + zw];
    }
#pragma unroll
    for (int off = 32; off > 0; off >>= 1) s += __shfl_down(s, off, 64);
    __shared__ float red[4];
    if ((tid & 63) == 0) red[tid >> 6] = s;
    __syncthreads();
    if (tid == 0)
        out[b] = 1.f / (1.f + expf(-(red[0] + red[1] + red[2] + red[3] + lb[0])));
}

extern "C" void kernel_launch(void* const* d_in, const int* in_sizes, int n_in,
                              void* d_out, int out_size, void* d_ws, size_t ws_size,
                              hipStream_t stream) {
    const float* X  = (const float*)d_in[0];
    const float* W  = (const float*)d_in[1];
    const float* cb = (const float*)d_in[2];
    const float* lw = (const float*)d_in[3];
    const float* lb = (const float*)d_in[4];
    float* out = (float*)d_out;
    char* ws = (char*)d_ws;
    float* C  = (float*)(ws + WS_C);
    u16* B2   = (u16*)(ws + WS_B2);
    u16* Xb   = (u16*)(ws + WS_XB);
    const bool fast = ws_size >= WS_FAST_NEED;

    if (fast) {
        build_b2_kernel<true><<<3254, 256, 0, stream>>>(W, B2, C);
        conv_bf16_kernel<<<9216, 256, 0, stream>>>(X, Xb);
        gemm_conv_fast<<<NBLK_FAST, 512, 0, stream>>>(Xb, B2, C);
    } else {
        build_b2_kernel<false><<<3254, 256, 0, stream>>>(W, B2, C);
        gemm_conv<false><<<NBLK, 512, 0, stream>>>(nullptr, X, B2, C);
    }
    epilogue_kernel<<<512, 256, 0, stream>>>(C, cb, lw, lb, out);
}

// Round 8
// 669.526 us; speedup vs baseline: 1.3580x; 1.0285x over previous
//
#include <hip/hip_runtime.h>

typedef unsigned short u16;
typedef __bf16 v8bf __attribute__((ext_vector_type(8)));
typedef float v4f __attribute__((ext_vector_type(4)));
typedef u16 v8u16 __attribute__((ext_vector_type(8)));

// ---------------- geometry constants ----------------
// X (input): [512][18][18][18*18] fp32, plane (z,w) = 324 contiguous
#define X_B 104976   // 18*18*324
#define X_A 5832     // 18*324
#define X_P 324
// Xb (bf16, padded plane 324->328 for 16B alignment of plane bases)
#define XB_B 106272  // 18*18*328
#define XB_A 5904    // 18*328
#define XB_P 328
// GEMM: M=18432 (b,x,y), N=112 (108 used: o*36+zo*6+wo), K'=169*352=59488
#define KP 59488
#define SLAB 352
#define NPAD 112
#define B2_ELEMS 6662656u    // 112*59488 == 13*143*3584 (B3 layout, same size)
// old slow-path grid
#define KSPLIT 7
#define NBLK (72 * KSPLIT)
// fast-path grid: 74 m-tiles (7 b = 252 rows each) x 13 kx-splits
#define MT_FAST 74
#define NBLK_FAST (74 * 13)
// ws layout (bytes)
#define WS_C   0
#define WS_B2  8257536ull
#define WS_XB  21582848ull
#define WS_FAST_NEED 130405504ull

__device__ __forceinline__ u16 f2bf(float f) {
    unsigned u = __builtin_bit_cast(unsigned, f);
    u += 0x7fffu + ((u >> 16) & 1u);   // RNE
    return (u16)(u >> 16);
}

#define AS1C(p) (const __attribute__((address_space(1))) void*)(p)
#define AS3(p)  (__attribute__((address_space(3))) void*)(p)
// s_waitcnt imm: vmcnt[3:0], expcnt[6:4]=7 (no wait), lgkmcnt[11:8]=15 (no wait)
#define WAIT_VM3 0x0F73
#define WAIT_VM0 0x0F70

// ---------------- merged prep: x->bf16 AND Toeplitz B3 AND zero C ----------
// Blocks [0,9216): fp32->bf16 padded-plane transcode of X.
// Blocks [9216,12470): build tile-contiguous pre-swizzled B3[kx][g][bslot*8+e]
//   (exact 7168B per-step B image; GEMM reads it as coalesced register frags)
//   + zero C. Independent work items merged so they overlap on the machine.
__global__ void prep_kernel(const float* __restrict__ X, u16* __restrict__ Xb,
                            const float* __restrict__ W, u16* __restrict__ B3,
                            float* __restrict__ C) {
    const int bx = blockIdx.x;
    if (bx < 9216) {
        // zero the 64-elem tail pad once (prevents NaN garbage * 0 in MFMA)
        if (bx == 0 && threadIdx.x < 64) Xb[54411264u + threadIdx.x] = 0;
        const long xbbase = (long)bx * XB_A;
        const long xfbase = (long)bx * X_A;
        for (int s = threadIdx.x; s < 738; s += 256) {
            int y = s / 41;                // 328/8 = 41 slots per plane row
            int pos = (s - y * 41) * 8;    // 0..320, multiple of 8
            const float* src = X + xfbase + y * 324 + pos;
            float4 lo = *(const float4*)src;                   // pos+3 <= 323 always
            float4 hi = (pos + 4 < 324) ? *(const float4*)(src + 4)
                                        : make_float4(0.f, 0.f, 0.f, 0.f);
            v8u16 p;
            p[0] = f2bf(lo.x); p[1] = f2bf(lo.y); p[2] = f2bf(lo.z); p[3] = f2bf(lo.w);
            p[4] = f2bf(hi.x); p[5] = f2bf(hi.y); p[6] = f2bf(hi.z); p[7] = f2bf(hi.w);
            *(v8u16*)(Xb + xbbase + s * 8) = p;
        }
    } else {
        unsigned t = (unsigned)(bx - 9216) * 256u + threadIdx.x;
        if (t < 516096u) ((float4*)C)[t] = make_float4(0.f, 0.f, 0.f, 0.f);
        if (t >= 832832u) return;          // B2_ELEMS/8 == 13*143*448
        unsigned kx = t / 64064u;          // 143*448
        unsigned r = t - kx * 64064u;
        unsigned g = r / 448u;
        unsigned bslot = r - g * 448u;
        unsigned n = bslot >> 2;
        unsigned chunk = (bslot & 3u) ^ ((bslot >> 3) & 3u);
        unsigned si = g / 13u, kyq = g - si * 13u;
        unsigned slab = kx * 13u + kyq;
        unsigned jj0 = si * 32u + chunk * 8u;
        v8u16 out = {0, 0, 0, 0, 0, 0, 0, 0};
        if (n < 108u && jj0 < 324u) {
            unsigned o = n / 36u, zw = n - o * 36u;
            unsigned zo = zw / 6u, wo = zw - zo * 6u;
            unsigned ky = slab - kx * 13u;
            const float* wb = W + o * 28561u + kx * 2197u + ky * 169u;
#pragma unroll
            for (int e = 0; e < 8; ++e) {
                unsigned jj = jj0 + e;
                if (jj < 324u) {
                    unsigned jz = jj / 18u, jw = jj - jz * 18u;
                    int dz = (int)jz - (int)zo, dw = (int)jw - (int)wo;
                    if (dz >= 0 && dz < 13 && dw >= 0 && dw < 13)
                        out[e] = f2bf(wb[dz * 13 + dw]);
                }
            }
        }
        ((v8u16*)B3)[t] = out;
    }
}

// ---------------- fast GEMM: kx-major, A in LDS, B streamed to registers ---
// R6 counters: 391us, Occ 42%, MfmaUtil 27% (~8% true pipe), LDS reads ~50% of
// step (72 b128/block-step, B 8x wave-redundant), stall-dominated 2-phase.
// This round: B LDS path removed. Each wave loads its 7 B frags per step
// directly from B3 into v8bf regs (per-lane addr = base + g*7168B + t*1024B,
// t-independent swizzle pos -> perfectly coalesced 1KB/wave segments, L2-hot
// 1MB/kx working set). Per-frag software pipeline: after the 2 MFMAs that
// consume b[t], issue next step's b[t] load (compiler emits vmcnt(6)-style
// counted waits; ~1-step = ~1000cyc lead covers L2/L3 latency). NO per-step
// barriers: barriers only at the 11 si boundaries (A-slice swap, full drain).
// LDS 48KB, target VGPR<=128 -> 2 blocks/CU, 16 waves.
__global__ __launch_bounds__(512, 4) void gemm_conv_fast(
    const u16* __restrict__ Xb, const u16* __restrict__ B3, float* __restrict__ C)
{
    // A slice: slot = bl*432 + p*4 + pos (p = prow*18+pcol; pos = chunk pos
    // after XOR swizzle). 3072 slots incl. 48 pad clones (uniform vm counts).
    __shared__ u16 Alds[3072 * 8];         // 49152 B only

    const int tid = threadIdx.x;
    const int lane = tid & 63;
    const int wv = tid >> 6;               // 0..7
    const int mt = blockIdx.x % MT_FAST;
    const int kx = blockIdx.x / MT_FAST;   // 0..12
    const int b0 = mt * 7;
    const int fc = lane >> 4;

    // ---- B register-frag base: frag t of step g at bptr + g*3584 + t*512 ----
    // row = t*16 + (lane&15); pos = fc ^ ((row>>1)&3) = fc ^ (((lane&15)>>1)&3)
    // (t-independent since (t*8)&3 == 0); elem = (row*4+pos)*8 = t*512 + laneoff.
    const u16* bptr = B3 + (size_t)kx * 512512u   // 143*3584
                    + ((lane & 15) * 4 + (fc ^ (((lane & 15) >> 1) & 3))) * 8;

    // ---- MFMA A-fragment bases ----
    int fr_base[2], fr_p0[2];
#pragma unroll
    for (int i = 0; i < 2; ++i) {
        int row = wv * 32 + i * 16 + (lane & 15);
        if (row > 251) row = 251;          // pad rows duplicate row 251 (masked at C-write)
        int bl = row / 36, xy = row - bl * 36;
        int x = xy / 6, y = xy - x * 6;
        fr_p0[i] = x * 18 + y;
        fr_base[i] = bl * 432;
    }

    // ---- A slice burst: j in [0,6), slot q = j*512 + tid ----
    auto stageA = [&](int si_, int j) {
        int q = j * 512 + tid;
        int qe = (q >= 3024) ? q - 3024 : q;    // pad slots clone slot 0..47
        int bl = qe / 432;                      // 0..6
        int rem = qe - bl * 432;
        int p = rem >> 2;                       // 0..107
        int pos = rem & 3;
        int c = pos ^ ((p >> 1) & 3);           // global chunk held at this pos
        int b = b0 + bl; if (b > 511) b = 511;  // tile 73 clamp
        int prow = p / 18;
        int pcol = p - prow * 18;
        const u16* gp = Xb + (b * XB_B + (kx + prow) * XB_A + pcol * XB_P
                              + si_ * 32 + c * 8);
        __builtin_amdgcn_global_load_lds(AS1C(gp),
            AS3(&Alds[(j * 512 + wv * 64) * 8]), 16, 0, 0);
    };

    v4f acc[2][7];
#pragma unroll
    for (int i = 0; i < 2; ++i)
#pragma unroll
        for (int t = 0; t < 7; ++t) acc[i][t] = (v4f){0.f, 0.f, 0.f, 0.f};

    // ---- prologue: A slice 0 burst + B batch 0 into regs; drain; publish ----
#pragma unroll
    for (int j = 0; j < 6; ++j) stageA(0, j);
    v8bf b[7];
#pragma unroll
    for (int t = 0; t < 7; ++t) b[t] = *(const v8bf*)(bptr + t * 512);
    __builtin_amdgcn_s_waitcnt(WAIT_VM0);
    __builtin_amdgcn_s_barrier();

    int si = 0, ky = 0;                    // step g = si*13 + ky

    for (int g = 0; g < 143; ++g) {
        // A fragments for this ky (LDS; compiler inserts lgkm waits)
        v8bf a0, a1;
        {
            int p = fr_p0[0] + ky;
            int slot = fr_base[0] + p * 4 + (fc ^ ((p >> 1) & 3));
            a0 = *(const v8bf*)(&Alds[slot * 8]);
        }
        {
            int p = fr_p0[1] + ky;
            int slot = fr_base[1] + p * 4 + (fc ^ ((p >> 1) & 3));
            a1 = *(const v8bf*)(&Alds[slot * 8]);
        }
        const u16* bnext = bptr + 3584;
        if (g < 142) {
#pragma unroll
            for (int t = 0; t < 7; ++t) {
                v8bf bt = b[t];
                acc[0][t] = __builtin_amdgcn_mfma_f32_16x16x32_bf16(a0, bt, acc[0][t], 0, 0, 0);
                acc[1][t] = __builtin_amdgcn_mfma_f32_16x16x32_bf16(a1, bt, acc[1][t], 0, 0, 0);
                b[t] = *(const v8bf*)(bnext + t * 512);   // prefetch next step's frag t
            }
        } else {
#pragma unroll
            for (int t = 0; t < 7; ++t) {
                acc[0][t] = __builtin_amdgcn_mfma_f32_16x16x32_bf16(a0, b[t], acc[0][t], 0, 0, 0);
                acc[1][t] = __builtin_amdgcn_mfma_f32_16x16x32_bf16(a1, b[t], acc[1][t], 0, 0, 0);
            }
        }
        bptr = bnext;

        if (++ky == 13) {
            ky = 0; ++si;
            if (si < 11) {
                __builtin_amdgcn_s_barrier();            // all waves done with slice si-1
#pragma unroll
                for (int j = 0; j < 6; ++j) stageA(si, j);
                __builtin_amdgcn_s_waitcnt(WAIT_VM0);    // drain A burst (B prefetch too - already needed)
                __builtin_amdgcn_s_barrier();            // publish slice si
            }
        }
    }

    // ---- split-K accumulate into C (mask pad rows 252..255 and tile-73 tail)
    const int colb = lane & 15;
    const int rq = (lane >> 4) * 4;
#pragma unroll
    for (int i = 0; i < 2; ++i) {
        int rl0 = wv * 32 + i * 16 + rq;
#pragma unroll
        for (int t = 0; t < 7; ++t) {
            int col = t * 16 + colb;
#pragma unroll
            for (int gq = 0; gq < 4; ++gq) {
                int lr = rl0 + gq;
                int grow = mt * 252 + lr;
                if (lr < 252 && grow < 18432)
                    atomicAdd(&C[grow * NPAD + col], acc[i][t][gq]);
            }
        }
    }
}

// ---------------- slow-path prep (fallback): row-major B2 + zero C ---------
__global__ void build_b2_kernel(const float* __restrict__ W, u16* __restrict__ B2,
                                float* __restrict__ C) {
    unsigned t = blockIdx.x * 256u + threadIdx.x;
    if (t < 516096u) ((float4*)C)[t] = make_float4(0.f, 0.f, 0.f, 0.f);
    if (t >= 832832u) return;              // B2_ELEMS/8
    unsigned n = t / 7436u;                // KP/8
    unsigned k0 = (t - n * 7436u) * 8u;
    unsigned slab = k0 / 352u;
    unsigned jj0 = k0 - slab * 352u;       // multiple of 8
    v8u16 out = {0, 0, 0, 0, 0, 0, 0, 0};
    if (n < 108u && jj0 < 324u) {
        unsigned kx = slab / 13u, ky = slab - kx * 13u;
        unsigned o = n / 36u, zw = n - o * 36u;
        unsigned zo = zw / 6u, wo = zw - zo * 6u;
        const float* wb = W + o * 28561u + kx * 2197u + ky * 169u;
#pragma unroll
        for (int e = 0; e < 8; ++e) {
            unsigned jj = jj0 + e;
            if (jj < 324u) {
                unsigned jz = jj / 18u, jw = jj - jz * 18u;
                int dz = (int)jz - (int)zo, dw = (int)jw - (int)wo;
                if (dz >= 0 && dz < 13 && dw >= 0 && dw < 13)
                    out[e] = f2bf(wb[dz * 13 + dw]);
            }
        }
    }
    ((v8u16*)B2)[t] = out;
}

// ---------------- slow-path GEMM (small-ws fallback, fp32 reg-staging) ----
__global__ __launch_bounds__(512, 4) void gemm_conv(
    const float* __restrict__ Xf, const u16* __restrict__ B2, float* __restrict__ C)
{
    __shared__ u16 Alds[3][256 * 32];
    __shared__ u16 Blds[3][112 * 32];

    const int tid = threadIdx.x;
    const int lane = tid & 63;
    const int wv = tid >> 6;
    const int bwv = (wv < 7) ? wv : 6;
    const int mt = blockIdx.x % 72;
    const int ks = blockIdx.x / 72;

    const int sbeg = (ks * 169) / KSPLIT;
    const int send = ((ks + 1) * 169) / KSPLIT;
    const int nsteps = (send - sbeg) * 11;

    int laneA[2], chunkA[2];
#pragma unroll
    for (int jr = 0; jr < 2; ++jr) {
        int slot = jr * 512 + tid;
        int row = slot >> 2;
        int chunk = (slot & 3) ^ ((slot >> 3) & 3);
        int r = mt * 256 + row;
        int b = r / 36;
        int xy = r - b * 36;
        int x = xy / 6;
        int y = xy - x * 6;
        laneA[jr] = b * X_B + x * X_A + y * X_P;
        chunkA[jr] = chunk;
    }
    const int bslot = bwv * 64 + lane;
    const int chunkB = (bslot & 3) ^ ((bslot >> 3) & 3);
    const int laneB = (bslot >> 2) * KP + chunkB * 8;

    v4f acc[2][7];
#pragma unroll
    for (int i = 0; i < 2; ++i)
#pragma unroll
        for (int t = 0; t < 7; ++t) acc[i][t] = (v4f){0.f, 0.f, 0.f, 0.f};

    auto stage = [&](int step, int p) {
        int q = step / 11;
        int si = step - q * 11;
        int slab = sbeg + q;
        int kx = slab / 13;
        int ky = slab - kx * 13;
        int aofs = kx * X_A + ky * X_P;
#pragma unroll
        for (int jr = 0; jr < 2; ++jr) {
            int jj0 = si * 32 + chunkA[jr] * 8;
            const float* gp = Xf + (laneA[jr] + aofs);
            float4 lo = make_float4(0.f, 0.f, 0.f, 0.f);
            float4 hi = make_float4(0.f, 0.f, 0.f, 0.f);
            if (jj0 < 324)     lo = *(const float4*)(gp + jj0);
            if (jj0 + 4 < 324) hi = *(const float4*)(gp + jj0 + 4);
            v8u16 pk;
            pk[0] = f2bf(lo.x); pk[1] = f2bf(lo.y); pk[2] = f2bf(lo.z); pk[3] = f2bf(lo.w);
            pk[4] = f2bf(hi.x); pk[5] = f2bf(hi.y); pk[6] = f2bf(hi.z); pk[7] = f2bf(hi.w);
            int slot = jr * 512 + tid;
            *(v8u16*)(&Alds[p][slot * 8]) = pk;
        }
        int bofs = slab * SLAB + si * 32;
        const u16* gp0 = B2 + (laneB + bofs);
        __builtin_amdgcn_global_load_lds(AS1C(gp0), AS3(&Blds[p][(bwv * 64) * 8]), 16, 0, 0);
    };

    stage(0, 0);
    stage(1, 1);

    for (int step = 0; step < nsteps; ++step) {
        const int p = step % 3;
        __builtin_amdgcn_s_waitcnt(0);
        __builtin_amdgcn_s_barrier();
        if (step + 2 < nsteps) stage(step + 2, (step + 2) % 3);

        v8bf a[2];
#pragma unroll
        for (int i = 0; i < 2; ++i) {
            int row = wv * 32 + i * 16 + (lane & 15);
            int slot = row * 4 + ((lane >> 4) ^ ((row >> 1) & 3));
            a[i] = *(const v8bf*)(&Alds[p][slot * 8]);
        }
#pragma unroll
        for (int t = 0; t < 7; ++t) {
            int row = t * 16 + (lane & 15);
            int slot = row * 4 + ((lane >> 4) ^ ((row >> 1) & 3));
            v8bf bb = *(const v8bf*)(&Blds[p][slot * 8]);
#pragma unroll
            for (int i = 0; i < 2; ++i)
                acc[i][t] = __builtin_amdgcn_mfma_f32_16x16x32_bf16(a[i], bb, acc[i][t], 0, 0, 0);
        }
    }

    const int colb = lane & 15;
    const int rq = (lane >> 4) * 4;
#pragma unroll
    for (int i = 0; i < 2; ++i) {
        int rowb = mt * 256 + wv * 32 + i * 16 + rq;
#pragma unroll
        for (int t = 0; t < 7; ++t) {
            int col = t * 16 + colb;
#pragma unroll
            for (int g = 0; g < 4; ++g)
                atomicAdd(&C[(rowb + g) * NPAD + col], acc[i][t][g]);
        }
    }
}

// ---------------- fused bias+ReLU+linear+sigmoid ----------------
__global__ void epilogue_kernel(const float* __restrict__ C, const float* __restrict__ cb,
                                const float* __restrict__ lw, const float* __restrict__ lb,
                                float* __restrict__ out) {
    const int b = blockIdx.x;
    const int tid = threadIdx.x;
    float s = 0.f;
    for (int t = tid; t < 3888; t += 256) {
        int xy = t / 108, n = t - xy * 108;
        int o = n / 36, zw = n - o * 36;
        int x = xy / 6, y = xy - x * 6;
        float c = C[(b * 36 + xy) * NPAD + n] + cb[o];
        s += fmaxf(c, 0.f) * lw[o * 1296 + x * 216 + y * 36 + zw];
    }
#pragma unroll
    for (int off = 32; off > 0; off >>= 1) s += __shfl_down(s, off, 64);
    __shared__ float red[4];
    if ((tid & 63) == 0) red[tid >> 6] = s;
    __syncthreads();
    if (tid == 0)
        out[b] = 1.f / (1.f + expf(-(red[0] + red[1] + red[2] + red[3] + lb[0])));
}

extern "C" void kernel_launch(void* const* d_in, const int* in_sizes, int n_in,
                              void* d_out, int out_size, void* d_ws, size_t ws_size,
                              hipStream_t stream) {
    const float* X  = (const float*)d_in[0];
    const float* W  = (const float*)d_in[1];
    const float* cb = (const float*)d_in[2];
    const float* lw = (const float*)d_in[3];
    const float* lb = (const float*)d_in[4];
    float* out = (float*)d_out;
    char* ws = (char*)d_ws;
    float* C  = (float*)(ws + WS_C);
    u16* B2   = (u16*)(ws + WS_B2);
    u16* Xb   = (u16*)(ws + WS_XB);
    const bool fast = ws_size >= WS_FAST_NEED;

    if (fast) {
        prep_kernel<<<12470, 256, 0, stream>>>(X, Xb, W, B2, C);
        gemm_conv_fast<<<NBLK_FAST, 512, 0, stream>>>(Xb, B2, C);
    } else {
        build_b2_kernel<<<3254, 256, 0, stream>>>(W, B2, C);
        gemm_conv<<<NBLK, 512, 0, stream>>>(X, B2, C);
    }
    epilogue_kernel<<<512, 256, 0, stream>>>(C, cb, lw, lb, out);
}

// Round 9
// 617.430 us; speedup vs baseline: 1.4726x; 1.0844x over previous
//
#include <hip/hip_runtime.h>

typedef unsigned short u16;
typedef __bf16 v8bf __attribute__((ext_vector_type(8)));
typedef float v4f __attribute__((ext_vector_type(4)));
typedef u16 v8u16 __attribute__((ext_vector_type(8)));

// ---------------- geometry constants ----------------
// X (input): [512][18][18][18*18] fp32, plane (z,w) = 324 contiguous
#define X_B 104976   // 18*18*324
#define X_A 5832     // 18*324
#define X_P 324
// Xb (bf16, padded plane 324->328 for 16B alignment of plane bases)
#define XB_B 106272  // 18*18*328
#define XB_A 5904    // 18*328
#define XB_P 328
// GEMM: M=18432 (b,x,y), N=112 (108 used: o*36+zo*6+wo), K'=169*352=59488
#define KP 59488
#define SLAB 352
#define NPAD 112
#define B2_ELEMS 6662656u    // 112*59488 == 13*143*3584 (B3 layout, same size)
// old slow-path grid
#define KSPLIT 7
#define NBLK (72 * KSPLIT)
// fast-path grid: 74 m-tiles (7 b = 252 rows each) x 13 kx-splits
#define MT_FAST 74
#define NBLK_FAST (74 * 13)
// ws layout (bytes)
#define WS_C   0
#define WS_B2  8257536ull
#define WS_XB  21582848ull
#define WS_FAST_NEED 130405504ull

__device__ __forceinline__ u16 f2bf(float f) {
    unsigned u = __builtin_bit_cast(unsigned, f);
    u += 0x7fffu + ((u >> 16) & 1u);   // RNE
    return (u16)(u >> 16);
}

#define AS1C(p) (const __attribute__((address_space(1))) void*)(p)
#define AS3(p)  (__attribute__((address_space(3))) void*)(p)
// s_waitcnt imm: vmcnt[3:0], expcnt[6:4]=7 (no wait), lgkmcnt[11:8]=15 (no wait)
#define WAIT_VM0 0x0F70

// ---------------- merged prep: x->bf16 AND Toeplitz B3 AND zero C ----------
// Blocks [0,9216): fp32->bf16 padded-plane transcode of X.
// Blocks [9216,12470): build tile-contiguous pre-swizzled B3[kx][g][bslot*8+e]
//   (exact 7168B per-step B image; GEMM reads it as coalesced register frags)
//   + zero C. Independent work items merged so they overlap on the machine.
__global__ void prep_kernel(const float* __restrict__ X, u16* __restrict__ Xb,
                            const float* __restrict__ W, u16* __restrict__ B3,
                            float* __restrict__ C) {
    const int bx = blockIdx.x;
    if (bx < 9216) {
        // zero the 64-elem tail pad once (prevents NaN garbage * 0 in MFMA)
        if (bx == 0 && threadIdx.x < 64) Xb[54411264u + threadIdx.x] = 0;
        const long xbbase = (long)bx * XB_A;
        const long xfbase = (long)bx * X_A;
        for (int s = threadIdx.x; s < 738; s += 256) {
            int y = s / 41;                // 328/8 = 41 slots per plane row
            int pos = (s - y * 41) * 8;    // 0..320, multiple of 8
            const float* src = X + xfbase + y * 324 + pos;
            float4 lo = *(const float4*)src;                   // pos+3 <= 323 always
            float4 hi = (pos + 4 < 324) ? *(const float4*)(src + 4)
                                        : make_float4(0.f, 0.f, 0.f, 0.f);
            v8u16 p;
            p[0] = f2bf(lo.x); p[1] = f2bf(lo.y); p[2] = f2bf(lo.z); p[3] = f2bf(lo.w);
            p[4] = f2bf(hi.x); p[5] = f2bf(hi.y); p[6] = f2bf(hi.z); p[7] = f2bf(hi.w);
            *(v8u16*)(Xb + xbbase + s * 8) = p;
        }
    } else {
        unsigned t = (unsigned)(bx - 9216) * 256u + threadIdx.x;
        if (t < 516096u) ((float4*)C)[t] = make_float4(0.f, 0.f, 0.f, 0.f);
        if (t >= 832832u) return;          // B2_ELEMS/8 == 13*143*448
        unsigned kx = t / 64064u;          // 143*448
        unsigned r = t - kx * 64064u;
        unsigned g = r / 448u;
        unsigned bslot = r - g * 448u;
        unsigned n = bslot >> 2;
        unsigned chunk = (bslot & 3u) ^ ((bslot >> 3) & 3u);
        unsigned si = g / 13u, kyq = g - si * 13u;
        unsigned slab = kx * 13u + kyq;
        unsigned jj0 = si * 32u + chunk * 8u;
        v8u16 out = {0, 0, 0, 0, 0, 0, 0, 0};
        if (n < 108u && jj0 < 324u) {
            unsigned o = n / 36u, zw = n - o * 36u;
            unsigned zo = zw / 6u, wo = zw - zo * 6u;
            unsigned ky = slab - kx * 13u;
            const float* wb = W + o * 28561u + kx * 2197u + ky * 169u;
#pragma unroll
            for (int e = 0; e < 8; ++e) {
                unsigned jj = jj0 + e;
                if (jj < 324u) {
                    unsigned jz = jj / 18u, jw = jj - jz * 18u;
                    int dz = (int)jz - (int)zo, dw = (int)jw - (int)wo;
                    if (dz >= 0 && dz < 13 && dw >= 0 && dw < 13)
                        out[e] = f2bf(wb[dz * 13 + dw]);
                }
            }
        }
        ((v8u16*)B3)[t] = out;
    }
}

// ---------------- fast GEMM: 4 waves x 64 rows, B streamed to registers ----
// R8 post-mortem: 365us; B reg-fill through L1 was the pipe (114KB/CU-step at
// ~64B/cyc = 1792cyc of the 3263 measured). B-bytes/CU-step = waves-per-rows x
// 7168B, invariant to everything except M-rows-per-wave. This round: 64 rows
// per wave (4 M-frags, acc[4][7] = 112 AGPRs), 256-thread blocks of 4 waves.
// B traffic halves to 57KB/CU-step (~896cyc); A LDS reads 512; matrix 272/SIMD.
// Regs ~70 VGPR + 112 AGPR < 256 -> 2 waves/SIMD (8 waves/CU, 2 blocks/CU).
// b-prefetch depth-1: frag t for step g+1 issued after the 4 MFMAs consuming
// b[t] at step g (28-MFMA lead covers L2 latency). Barriers only at the 11
// si boundaries (A-slice swap, full vm drain).
__global__ __launch_bounds__(256, 2) void gemm_conv_fast(
    const u16* __restrict__ Xb, const u16* __restrict__ B3, float* __restrict__ C)
{
    // A slice: slot = bl*432 + p*4 + pos (p = prow*18+pcol; pos = chunk pos
    // after XOR swizzle). 3072 slots incl. 48 pad clones (uniform vm counts).
    __shared__ u16 Alds[3072 * 8];         // 49152 B

    const int tid = threadIdx.x;
    const int lane = tid & 63;
    const int wv = tid >> 6;               // 0..3
    const int mt = blockIdx.x % MT_FAST;
    const int kx = blockIdx.x / MT_FAST;   // 0..12
    const int b0 = mt * 7;
    const int fc = lane >> 4;

    // ---- B register-frag base: frag t of step g at bptr + g*3584 + t*512 ----
    // row = t*16 + (lane&15); pos = fc ^ (((lane&15)>>1)&3) (t-independent);
    // elem = (row*4+pos)*8 = t*512 + laneoff. All 4 waves read the same tile.
    const u16* bptr = B3 + (size_t)kx * 512512u   // 143*3584
                    + ((lane & 15) * 4 + (fc ^ (((lane & 15) >> 1) & 3))) * 8;

    // ---- MFMA A-fragment bases: wave covers rows wv*64 .. wv*64+63 ----
    int fr_base[4], fr_p0[4];
#pragma unroll
    for (int i = 0; i < 4; ++i) {
        int row = wv * 64 + i * 16 + (lane & 15);
        if (row > 251) row = 251;          // pad rows duplicate row 251 (masked at C-write)
        int bl = row / 36, xy = row - bl * 36;
        int x = xy / 6, y = xy - x * 6;
        fr_p0[i] = x * 18 + y;
        fr_base[i] = bl * 432;
    }

    // ---- A slice burst: j in [0,12), slot q = j*256 + tid ----
    auto stageA = [&](int si_, int j) {
        int q = j * 256 + tid;
        int qe = (q >= 3024) ? q - 3024 : q;    // pad slots clone slot 0..47
        int bl = qe / 432;                      // 0..6
        int rem = qe - bl * 432;
        int p = rem >> 2;                       // 0..107
        int pos = rem & 3;
        int c = pos ^ ((p >> 1) & 3);           // global chunk held at this pos
        int b = b0 + bl; if (b > 511) b = 511;  // tile 73 clamp
        int prow = p / 18;
        int pcol = p - prow * 18;
        const u16* gp = Xb + (b * XB_B + (kx + prow) * XB_A + pcol * XB_P
                              + si_ * 32 + c * 8);
        __builtin_amdgcn_global_load_lds(AS1C(gp),
            AS3(&Alds[(j * 256 + wv * 64) * 8]), 16, 0, 0);
    };

    v4f acc[4][7];
#pragma unroll
    for (int i = 0; i < 4; ++i)
#pragma unroll
        for (int t = 0; t < 7; ++t) acc[i][t] = (v4f){0.f, 0.f, 0.f, 0.f};

    // ---- prologue: A slice 0 burst + B batch 0 into regs; drain; publish ----
#pragma unroll
    for (int j = 0; j < 12; ++j) stageA(0, j);
    v8bf b[7];
#pragma unroll
    for (int t = 0; t < 7; ++t) b[t] = *(const v8bf*)(bptr + t * 512);
    __builtin_amdgcn_s_waitcnt(WAIT_VM0);
    __builtin_amdgcn_s_barrier();

    int si = 0, ky = 0;                    // step g = si*13 + ky

    for (int g = 0; g < 143; ++g) {
        // A fragments for this ky (LDS; compiler inserts lgkm waits)
        v8bf a[4];
#pragma unroll
        for (int i = 0; i < 4; ++i) {
            int p = fr_p0[i] + ky;
            int slot = fr_base[i] + p * 4 + (fc ^ ((p >> 1) & 3));
            a[i] = *(const v8bf*)(&Alds[slot * 8]);
        }
        const u16* bnext = bptr + 3584;
        if (g < 142) {
#pragma unroll
            for (int t = 0; t < 7; ++t) {
                v8bf bt = b[t];
                acc[0][t] = __builtin_amdgcn_mfma_f32_16x16x32_bf16(a[0], bt, acc[0][t], 0, 0, 0);
                acc[1][t] = __builtin_amdgcn_mfma_f32_16x16x32_bf16(a[1], bt, acc[1][t], 0, 0, 0);
                acc[2][t] = __builtin_amdgcn_mfma_f32_16x16x32_bf16(a[2], bt, acc[2][t], 0, 0, 0);
                acc[3][t] = __builtin_amdgcn_mfma_f32_16x16x32_bf16(a[3], bt, acc[3][t], 0, 0, 0);
                b[t] = *(const v8bf*)(bnext + t * 512);   // prefetch next step's frag t
            }
        } else {
#pragma unroll
            for (int t = 0; t < 7; ++t) {
                acc[0][t] = __builtin_amdgcn_mfma_f32_16x16x32_bf16(a[0], b[t], acc[0][t], 0, 0, 0);
                acc[1][t] = __builtin_amdgcn_mfma_f32_16x16x32_bf16(a[1], b[t], acc[1][t], 0, 0, 0);
                acc[2][t] = __builtin_amdgcn_mfma_f32_16x16x32_bf16(a[2], b[t], acc[2][t], 0, 0, 0);
                acc[3][t] = __builtin_amdgcn_mfma_f32_16x16x32_bf16(a[3], b[t], acc[3][t], 0, 0, 0);
            }
        }
        bptr = bnext;

        if (++ky == 13) {
            ky = 0; ++si;
            if (si < 11) {
                __builtin_amdgcn_s_barrier();            // all waves done with slice si-1
#pragma unroll
                for (int j = 0; j < 12; ++j) stageA(si, j);
                __builtin_amdgcn_s_waitcnt(WAIT_VM0);    // drain A burst (+ b prefetch, harmless)
                __builtin_amdgcn_s_barrier();            // publish slice si
            }
        }
    }

    // ---- split-K accumulate into C (mask pad rows 252..255 and tile-73 tail)
    const int colb = lane & 15;
    const int rq = (lane >> 4) * 4;
#pragma unroll
    for (int i = 0; i < 4; ++i) {
        int rl0 = wv * 64 + i * 16 + rq;
#pragma unroll
        for (int t = 0; t < 7; ++t) {
            int col = t * 16 + colb;
#pragma unroll
            for (int gq = 0; gq < 4; ++gq) {
                int lr = rl0 + gq;
                int grow = mt * 252 + lr;
                if (lr < 252 && grow < 18432)
                    atomicAdd(&C[grow * NPAD + col], acc[i][t][gq]);
            }
        }
    }
}

// ---------------- slow-path prep (fallback): row-major B2 + zero C ---------
__global__ void build_b2_kernel(const float* __restrict__ W, u16* __restrict__ B2,
                                float* __restrict__ C) {
    unsigned t = blockIdx.x * 256u + threadIdx.x;
    if (t < 516096u) ((float4*)C)[t] = make_float4(0.f, 0.f, 0.f, 0.f);
    if (t >= 832832u) return;              // B2_ELEMS/8
    unsigned n = t / 7436u;                // KP/8
    unsigned k0 = (t - n * 7436u) * 8u;
    unsigned slab = k0 / 352u;
    unsigned jj0 = k0 - slab * 352u;       // multiple of 8
    v8u16 out = {0, 0, 0, 0, 0, 0, 0, 0};
    if (n < 108u && jj0 < 324u) {
        unsigned kx = slab / 13u, ky = slab - kx * 13u;
        unsigned o = n / 36u, zw = n - o * 36u;
        unsigned zo = zw / 6u, wo = zw - zo * 6u;
        const float* wb = W + o * 28561u + kx * 2197u + ky * 169u;
#pragma unroll
        for (int e = 0; e < 8; ++e) {
            unsigned jj = jj0 + e;
            if (jj < 324u) {
                unsigned jz = jj / 18u, jw = jj - jz * 18u;
                int dz = (int)jz - (int)zo, dw = (int)jw - (int)wo;
                if (dz >= 0 && dz < 13 && dw >= 0 && dw < 13)
                    out[e] = f2bf(wb[dz * 13 + dw]);
            }
        }
    }
    ((v8u16*)B2)[t] = out;
}

// ---------------- slow-path GEMM (small-ws fallback, fp32 reg-staging) ----
__global__ __launch_bounds__(512, 4) void gemm_conv(
    const float* __restrict__ Xf, const u16* __restrict__ B2, float* __restrict__ C)
{
    __shared__ u16 Alds[3][256 * 32];
    __shared__ u16 Blds[3][112 * 32];

    const int tid = threadIdx.x;
    const int lane = tid & 63;
    const int wv = tid >> 6;
    const int bwv = (wv < 7) ? wv : 6;
    const int mt = blockIdx.x % 72;
    const int ks = blockIdx.x / 72;

    const int sbeg = (ks * 169) / KSPLIT;
    const int send = ((ks + 1) * 169) / KSPLIT;
    const int nsteps = (send - sbeg) * 11;

    int laneA[2], chunkA[2];
#pragma unroll
    for (int jr = 0; jr < 2; ++jr) {
        int slot = jr * 512 + tid;
        int row = slot >> 2;
        int chunk = (slot & 3) ^ ((slot >> 3) & 3);
        int r = mt * 256 + row;
        int b = r / 36;
        int xy = r - b * 36;
        int x = xy / 6;
        int y = xy - x * 6;
        laneA[jr] = b * X_B + x * X_A + y * X_P;
        chunkA[jr] = chunk;
    }
    const int bslot = bwv * 64 + lane;
    const int chunkB = (bslot & 3) ^ ((bslot >> 3) & 3);
    const int laneB = (bslot >> 2) * KP + chunkB * 8;

    v4f acc[2][7];
#pragma unroll
    for (int i = 0; i < 2; ++i)
#pragma unroll
        for (int t = 0; t < 7; ++t) acc[i][t] = (v4f){0.f, 0.f, 0.f, 0.f};

    auto stage = [&](int step, int p) {
        int q = step / 11;
        int si = step - q * 11;
        int slab = sbeg + q;
        int kx = slab / 13;
        int ky = slab - kx * 13;
        int aofs = kx * X_A + ky * X_P;
#pragma unroll
        for (int jr = 0; jr < 2; ++jr) {
            int jj0 = si * 32 + chunkA[jr] * 8;
            const float* gp = Xf + (laneA[jr] + aofs);
            float4 lo = make_float4(0.f, 0.f, 0.f, 0.f);
            float4 hi = make_float4(0.f, 0.f, 0.f, 0.f);
            if (jj0 < 324)     lo = *(const float4*)(gp + jj0);
            if (jj0 + 4 < 324) hi = *(const float4*)(gp + jj0 + 4);
            v8u16 pk;
            pk[0] = f2bf(lo.x); pk[1] = f2bf(lo.y); pk[2] = f2bf(lo.z); pk[3] = f2bf(lo.w);
            pk[4] = f2bf(hi.x); pk[5] = f2bf(hi.y); pk[6] = f2bf(hi.z); pk[7] = f2bf(hi.w);
            int slot = jr * 512 + tid;
            *(v8u16*)(&Alds[p][slot * 8]) = pk;
        }
        int bofs = slab * SLAB + si * 32;
        const u16* gp0 = B2 + (laneB + bofs);
        __builtin_amdgcn_global_load_lds(AS1C(gp0), AS3(&Blds[p][(bwv * 64) * 8]), 16, 0, 0);
    };

    stage(0, 0);
    stage(1, 1);

    for (int step = 0; step < nsteps; ++step) {
        const int p = step % 3;
        __builtin_amdgcn_s_waitcnt(0);
        __builtin_amdgcn_s_barrier();
        if (step + 2 < nsteps) stage(step + 2, (step + 2) % 3);

        v8bf a[2];
#pragma unroll
        for (int i = 0; i < 2; ++i) {
            int row = wv * 32 + i * 16 + (lane & 15);
            int slot = row * 4 + ((lane >> 4) ^ ((row >> 1) & 3));
            a[i] = *(const v8bf*)(&Alds[p][slot * 8]);
        }
#pragma unroll
        for (int t = 0; t < 7; ++t) {
            int row = t * 16 + (lane & 15);
            int slot = row * 4 + ((lane >> 4) ^ ((row >> 1) & 3));
            v8bf bb = *(const v8bf*)(&Blds[p][slot * 8]);
#pragma unroll
            for (int i = 0; i < 2; ++i)
                acc[i][t] = __builtin_amdgcn_mfma_f32_16x16x32_bf16(a[i], bb, acc[i][t], 0, 0, 0);
        }
    }

    const int colb = lane & 15;
    const int rq = (lane >> 4) * 4;
#pragma unroll
    for (int i = 0; i < 2; ++i) {
        int rowb = mt * 256 + wv * 32 + i * 16 + rq;
#pragma unroll
        for (int t = 0; t < 7; ++t) {
            int col = t * 16 + colb;
#pragma unroll
            for (int g = 0; g < 4; ++g)
                atomicAdd(&C[(rowb + g) * NPAD + col], acc[i][t][g]);
        }
    }
}

// ---------------- fused bias+ReLU+linear+sigmoid ----------------
__global__ void epilogue_kernel(const float* __restrict__ C, const float* __restrict__ cb,
                                const float* __restrict__ lw, const float* __restrict__ lb,
                                float* __restrict__ out) {
    const int b = blockIdx.x;
    const int tid = threadIdx.x;
    float s = 0.f;
    for (int t = tid; t < 3888; t += 256) {
        int xy = t / 108, n = t - xy * 108;
        int o = n / 36, zw = n - o * 36;
        int x = xy / 6, y = xy - x * 6;
        float c = C[(b * 36 + xy) * NPAD + n] + cb[o];
        s += fmaxf(c, 0.f) * lw[o * 1296 + x * 216 + y * 36 + zw];
    }
#pragma unroll
    for (int off = 32; off > 0; off >>= 1) s += __shfl_down(s, off, 64);
    __shared__ float red[4];
    if ((tid & 63) == 0) red[tid >> 6] = s;
    __syncthreads();
    if (tid == 0)
        out[b] = 1.f / (1.f + expf(-(red[0] + red[1] + red[2] + red[3] + lb[0])));
}

extern "C" void kernel_launch(void* const* d_in, const int* in_sizes, int n_in,
                              void* d_out, int out_size, void* d_ws, size_t ws_size,
                              hipStream_t stream) {
    const float* X  = (const float*)d_in[0];
    const float* W  = (const float*)d_in[1];
    const float* cb = (const float*)d_in[2];
    const float* lw = (const float*)d_in[3];
    const float* lb = (const float*)d_in[4];
    float* out = (float*)d_out;
    char* ws = (char*)d_ws;
    float* C  = (float*)(ws + WS_C);
    u16* B2   = (u16*)(ws + WS_B2);
    u16* Xb   = (u16*)(ws + WS_XB);
    const bool fast = ws_size >= WS_FAST_NEED;

    if (fast) {
        prep_kernel<<<12470, 256, 0, stream>>>(X, Xb, W, B2, C);
        gemm_conv_fast<<<NBLK_FAST, 256, 0, stream>>>(Xb, B2, C);
    } else {
        build_b2_kernel<<<3254, 256, 0, stream>>>(W, B2, C);
        gemm_conv<<<NBLK, 512, 0, stream>>>(X, B2, C);
    }
    epilogue_kernel<<<512, 256, 0, stream>>>(C, cb, lw, lb, out);
}